// Round 19
// baseline (44.986 us; speedup 1.0000x reference)
//
#include <hip/hip_runtime.h>
#include <math.h>

#define CDIM   862
#define NRANK  8
#define KW     7
#define ROWS_PER_BLOCK 4
#define THREADS (ROWS_PER_BLOCK * 64)
#define LN_EPS 1e-5f
#define NPAIRT 13            // 13 double-tiles cover elements 0..831
#define XH_LEN 880           // shorts: [0..3] zero pad, [4+i]=bf16(x[i]), zeros to 879
#define XY_LEN 866           // f32: x (later overwritten by pre-norm y), + pad

typedef __attribute__((ext_vector_type(8)))  short bf16x8;
typedef __attribute__((ext_vector_type(16))) float f32x16;

static __device__ __forceinline__ unsigned rne_bf16(float f) {
    const unsigned u = __float_as_uint(f);
    return (u + 0x7FFFu + ((u >> 16) & 1u)) >> 16;   // round-to-nearest-even
}

// One wave = one row. Double-tile MFMA -- EXACT r16-passed structure
// (two-shuffle combine, rolled tile loop, rne_bf16 staging) with ONLY two
// provably-exact edits:
//   1. bdown dropped: uniform per-row shift cancels identically in LayerNorm.
//   2. exp2f(z) with log2e-pre-scaled constants: exp2 is the native HW exp
//      (v_exp_f32 computes 2^x), deleting 8 v_mul/element vs __expf.
// r17/r18's single-shuffle combine and unroll-2 are QUARANTINED (one of them
// broke validation at 0.547/0.64; to be isolated later, not bundled).
__global__ __launch_bounds__(THREADS) void cvmc_kernel(
    const float* __restrict__ x,
    const float* __restrict__ Wup,
    const float* __restrict__ bup,
    const float* __restrict__ Wdown,
    const float* __restrict__ bdown,
    const float* __restrict__ gamma,
    const float* __restrict__ beta,
    float* __restrict__ out)
{
    const int lane = threadIdx.x & 63;
    const int wv   = threadIdx.x >> 6;
    const int row  = blockIdx.x * ROWS_PER_BLOCK + wv;

    __shared__ short sxh[ROWS_PER_BLOCK][XH_LEN];
    __shared__ float sxy[ROWS_PER_BLOCK][XY_LEN];

    const int hh    = lane >> 5;
    const int l31   = lane & 31;
    const int rbase = 4 * hh;          // this half-wave's rank group
    float bu4[4], wd4[4];
#pragma unroll
    for (int q = 0; q < 4; ++q) {
        bu4[q] = bup[rbase + q];
        wd4[q] = Wdown[rbase + q];
    }

    // ---- A fragment: rows 0-7 @ k=0..6 (hh=0 slots), rows 8-15 @ k=8..14 (hh=1) ----
    bf16x8 afrag;
    {
        const bool use = (hh == 0) ? (l31 < NRANK) : (l31 >= 8 && l31 < 8 + NRANK);
        const int  rr  = (hh == 0) ? l31 : (l31 - 8);
#pragma unroll
        for (int j = 0; j < 8; ++j) {
            float wvv = (use && j < KW) ? Wup[rr * KW + j] : 0.0f;
            afrag[j] = (short)(rne_bf16(wvv) & 0xFFFFu);
        }
    }

    // ---- C operand: bias per D row (rank = (q&3)+rbase for q<8), rest 0 ----
    f32x16 cin;
#pragma unroll
    for (int i = 0; i < 16; ++i) cin[i] = 0.0f;
#pragma unroll
    for (int q = 0; q < 8; ++q) cin[q] = bu4[q & 3];

    // ---- stage row: sxy = f32 x, sxh = bf16(RNE bit-twiddle) with left pad ----
    {
        const float2* __restrict__ xr2 =
            reinterpret_cast<const float2*>(x + (size_t)row * CDIM);
        unsigned* xhW = reinterpret_cast<unsigned*>(&sxh[wv][0]);
#pragma unroll
        for (int qq = 0; qq < 7; ++qq) {
            const int i = lane + 64 * qq;               // float2 pair index
            if (i < CDIM / 2) {
                float2 v = xr2[i];
                *reinterpret_cast<float2*>(&sxy[wv][2 * i]) = v;
                xhW[2 + i] = rne_bf16(v.x) | (rne_bf16(v.y) << 16);
            }
        }
        if (lane < 2)       xhW[lane] = 0u;             // shorts 0..3 (left halo)
        else if (lane < 9)  xhW[431 + lane] = 0u;       // shorts 866..879 zero
        else if (lane < 13) sxy[wv][862 + (lane - 9)] = 0.0f;
    }
    // wave-private LDS slice; same-wave DS ops are in issue order -> no barrier

    // gelu(t) ~ t*sigmoid(1.5957691 t + 0.0713548 t^3); u = 1 + 2^z, z pre-scaled
    const float C1 = -0.0713548162f * 1.44269504088896340736f;
    const float C0 = -1.5957691216f * 1.44269504088896340736f;

    const unsigned* xhD = reinterpret_cast<const unsigned*>(&sxh[wv][0]);

    // per-4-rank GELU + down-proj partial (exp2f = native 2^x)
    auto dp4 = [&](float t0, float t1, float t2, float t3) -> float {
        const float z0 = t0 * fmaf(t0 * t0, C1, C0);
        const float z1 = t1 * fmaf(t1 * t1, C1, C0);
        const float z2 = t2 * fmaf(t2 * t2, C1, C0);
        const float z3 = t3 * fmaf(t3 * t3, C1, C0);
        const float u0 = 1.0f + exp2f(z0);
        const float u1 = 1.0f + exp2f(z1);
        const float u2 = 1.0f + exp2f(z2);
        const float u3 = 1.0f + exp2f(z3);
        const float r01 = __builtin_amdgcn_rcpf(u0 * u1);
        const float r23 = __builtin_amdgcn_rcpf(u2 * u3);
        float n0 = (wd4[0] * t0) * u1; n0 = fmaf(wd4[1] * t1, u0, n0);
        float n1 = (wd4[2] * t2) * u3; n1 = fmaf(wd4[3] * t3, u2, n1);
        float p  = n0 * r01;
        return fmaf(n1, r23, p);
    };

    float sum = 0.0f, sumsq = 0.0f;

    for (int s = 0; s < NPAIRT; ++s) {
        const int cw = 64 * s + lane;      // this lane's window element (= its y element)
        const int ws = cw + 1;             // short index of x[cw-3] in sxh

        const unsigned* pw = xhD + (ws >> 1);
        const unsigned sh = (unsigned)(ws & 1) * 16u;   // 0 or 16 (5-bit safe)
        const unsigned q0 = pw[0], q1 = pw[1], q2 = pw[2], q3 = pw[3], q4 = pw[4];
        union { unsigned u[4]; bf16x8 v; } bfr;
        bfr.u[0] = __builtin_amdgcn_alignbit(q1, q0, sh);
        bfr.u[1] = __builtin_amdgcn_alignbit(q2, q1, sh);
        bfr.u[2] = __builtin_amdgcn_alignbit(q3, q2, sh);
        bfr.u[3] = __builtin_amdgcn_alignbit(q4, q3, sh);

        f32x16 d = __builtin_amdgcn_mfma_f32_32x32x16_bf16(afrag, bfr.v, cin, 0, 0, 0);

        // d[0..3]: ranks rbase.. of eA=64s+l31 ; d[4..7]: same ranks of eB=eA+32
        const float pA = dp4(d[0], d[1], d[2], d[3]);
        const float pB = dp4(d[4], d[5], d[6], d[7]);
        const float hA = pA + __shfl_xor(pA, 32, 64);
        const float hB = pB + __shfl_xor(pB, 32, 64);
        const float h  = (hh == 0) ? hA : hB;          // this lane's element = cw

        const float xv = sxy[wv][cw];
        const float y  = xv + h;           // residual (bdown cancels in LN)
        sxy[wv][cw] = y;
        sum += y;
        sumsq = fmaf(y, y, sumsq);
    }

    // ---- tail tile: elements 832..861 (single-tile path, halves duplicate) ----
    {
        const int c  = 832 + l31;
        const int ws = c + 1;
        const unsigned* pw = xhD + (ws >> 1);
        const unsigned sh = (unsigned)(ws & 1) * 16u;
        const unsigned q0 = pw[0], q1 = pw[1], q2 = pw[2], q3 = pw[3], q4 = pw[4];
        union { unsigned u[4]; bf16x8 v; } bfr;
        bfr.u[0] = __builtin_amdgcn_alignbit(q1, q0, sh);
        bfr.u[1] = __builtin_amdgcn_alignbit(q2, q1, sh);
        bfr.u[2] = __builtin_amdgcn_alignbit(q3, q2, sh);
        bfr.u[3] = __builtin_amdgcn_alignbit(q4, q3, sh);

        f32x16 d = __builtin_amdgcn_mfma_f32_32x32x16_bf16(afrag, bfr.v, cin, 0, 0, 0);

        const float p = dp4(d[0], d[1], d[2], d[3]);
        const float psum = p + __shfl_xor(p, 32, 64);
        const float y = sxy[wv][c] + psum;
        if (hh == 0 && c < CDIM) {                     // single-counted
            sxy[wv][c] = y;
            sum += y;
            sumsq = fmaf(y, y, sumsq);
        }
    }

    // in-wave butterfly: every lane ends with the row totals
#pragma unroll
    for (int off = 1; off < 64; off <<= 1) {
        sum   += __shfl_xor(sum, off, 64);
        sumsq += __shfl_xor(sumsq, off, 64);
    }

    const float inv  = 1.0f / (float)CDIM;
    const float mu   = sum * inv;
    const float var  = fmaf(sumsq, inv, -mu * mu);
    const float rstd = rsqrtf(var + LN_EPS);

    // coalesced epilogue: contiguous float2 reads from LDS, float2 stores
    float2* __restrict__ yr2 = reinterpret_cast<float2*>(out + (size_t)row * CDIM);
    const float2* __restrict__ g2 = reinterpret_cast<const float2*>(gamma);
    const float2* __restrict__ b2 = reinterpret_cast<const float2*>(beta);
#pragma unroll
    for (int qq = 0; qq < 7; ++qq) {
        const int i = lane + 64 * qq;
        if (i < CDIM / 2) {
            const float2 yv = *reinterpret_cast<const float2*>(&sxy[wv][2 * i]);
            const float2 gv = g2[i];
            const float2 bv = b2[i];
            float2 o;
            o.x = fmaf((yv.x - mu) * rstd, gv.x, bv.x);
            o.y = fmaf((yv.y - mu) * rstd, gv.y, bv.y);
            yr2[i] = o;
        }
    }
}

extern "C" void kernel_launch(void* const* d_in, const int* in_sizes, int n_in,
                              void* d_out, int out_size, void* d_ws, size_t ws_size,
                              hipStream_t stream) {
    const float* x     = (const float*)d_in[0];
    const float* Wup   = (const float*)d_in[1];
    const float* bup   = (const float*)d_in[2];
    const float* Wdown = (const float*)d_in[3];
    const float* bdown = (const float*)d_in[4];   // cancels in LayerNorm; unused
    const float* gamma = (const float*)d_in[5];
    const float* beta  = (const float*)d_in[6];
    float* out = (float*)d_out;
    (void)bdown;

    const int nrows = out_size / CDIM;                 // 11520 (divisible by 4)
    const int nblk  = nrows / ROWS_PER_BLOCK;          // 2880
    cvmc_kernel<<<nblk, THREADS, 0, stream>>>(x, Wup, bup, Wdown, bdown,
                                              gamma, beta, out);
}

// Round 20
// 36.987 us; speedup vs baseline: 1.2163x; 1.2163x over previous
//
#include <hip/hip_runtime.h>
#include <math.h>

#define CDIM   862
#define NRANK  8
#define KW     7
#define ROWS_PER_BLOCK 4
#define THREADS (ROWS_PER_BLOCK * 64)
#define LN_EPS 1e-5f
#define NPAIRT 13            // 13 double-tiles cover elements 0..831
#define XH_LEN 880           // shorts: [0..3] zero pad, [4+i]=bf16(x[i]), zeros to 879
#define XY_LEN 866           // f32: x (later overwritten by pre-norm y), + pad

typedef __attribute__((ext_vector_type(8)))  short bf16x8;
typedef __attribute__((ext_vector_type(16))) float f32x16;

static __device__ __forceinline__ unsigned rne_bf16(float f) {
    const unsigned u = __float_as_uint(f);
    return (u + 0x7FFFu + ((u >> 16) & 1u)) >> 16;   // round-to-nearest-even
}

// Native 2^x: v_exp_f32 IS exp2 on gfx950. libm exp2f (r19) was the ocml
// correctly-rounded path: +8 VGPR and ~17% slower. Fallback is exact math.
#if __has_builtin(__builtin_amdgcn_exp2f)
#define EXP2F(x) __builtin_amdgcn_exp2f(x)
#else
#define EXP2F(x) __expf((x) * 0.69314718055994530942f)
#endif

// One wave = one row. Double-tile MFMA -- EXACT r16-passed structure
// (two-shuffle combine, rolled tile loop, rne_bf16 staging). Changes vs r16:
//   1. bdown dropped (uniform row shift cancels exactly in LayerNorm; passed r19)
//   2. native exp2 builtin with log2e-pre-scaled constants (deletes the
//      per-call v_mul that __expf emits; r19 proved libm exp2f is NOT this)
// Single-shuffle combine and unroll-2 remain QUARANTINED (r17/r18 failures).
__global__ __launch_bounds__(THREADS) void cvmc_kernel(
    const float* __restrict__ x,
    const float* __restrict__ Wup,
    const float* __restrict__ bup,
    const float* __restrict__ Wdown,
    const float* __restrict__ bdown,
    const float* __restrict__ gamma,
    const float* __restrict__ beta,
    float* __restrict__ out)
{
    const int lane = threadIdx.x & 63;
    const int wv   = threadIdx.x >> 6;
    const int row  = blockIdx.x * ROWS_PER_BLOCK + wv;

    __shared__ short sxh[ROWS_PER_BLOCK][XH_LEN];
    __shared__ float sxy[ROWS_PER_BLOCK][XY_LEN];

    const int hh    = lane >> 5;
    const int l31   = lane & 31;
    const int rbase = 4 * hh;          // this half-wave's rank group
    float bu4[4], wd4[4];
#pragma unroll
    for (int q = 0; q < 4; ++q) {
        bu4[q] = bup[rbase + q];
        wd4[q] = Wdown[rbase + q];
    }

    // ---- A fragment: rows 0-7 @ k=0..6 (hh=0 slots), rows 8-15 @ k=8..14 (hh=1) ----
    bf16x8 afrag;
    {
        const bool use = (hh == 0) ? (l31 < NRANK) : (l31 >= 8 && l31 < 8 + NRANK);
        const int  rr  = (hh == 0) ? l31 : (l31 - 8);
#pragma unroll
        for (int j = 0; j < 8; ++j) {
            float wvv = (use && j < KW) ? Wup[rr * KW + j] : 0.0f;
            afrag[j] = (short)(rne_bf16(wvv) & 0xFFFFu);
        }
    }

    // ---- C operand: bias per D row (rank = (q&3)+rbase for q<8), rest 0 ----
    f32x16 cin;
#pragma unroll
    for (int i = 0; i < 16; ++i) cin[i] = 0.0f;
#pragma unroll
    for (int q = 0; q < 8; ++q) cin[q] = bu4[q & 3];

    // ---- stage row: sxy = f32 x, sxh = bf16(RNE bit-twiddle) with left pad ----
    {
        const float2* __restrict__ xr2 =
            reinterpret_cast<const float2*>(x + (size_t)row * CDIM);
        unsigned* xhW = reinterpret_cast<unsigned*>(&sxh[wv][0]);
#pragma unroll
        for (int qq = 0; qq < 7; ++qq) {
            const int i = lane + 64 * qq;               // float2 pair index
            if (i < CDIM / 2) {
                float2 v = xr2[i];
                *reinterpret_cast<float2*>(&sxy[wv][2 * i]) = v;
                xhW[2 + i] = rne_bf16(v.x) | (rne_bf16(v.y) << 16);
            }
        }
        if (lane < 2)       xhW[lane] = 0u;             // shorts 0..3 (left halo)
        else if (lane < 9)  xhW[431 + lane] = 0u;       // shorts 866..879 zero
        else if (lane < 13) sxy[wv][862 + (lane - 9)] = 0.0f;
    }
    // wave-private LDS slice; same-wave DS ops are in issue order -> no barrier

    // gelu(t) ~ t*sigmoid(1.5957691 t + 0.0713548 t^3); u = 1 + 2^z, z pre-scaled by log2e
    const float C1 = -0.0713548162f * 1.44269504088896340736f;
    const float C0 = -1.5957691216f * 1.44269504088896340736f;

    const unsigned* xhD = reinterpret_cast<const unsigned*>(&sxh[wv][0]);

    // per-4-rank GELU + down-proj partial (native exp2)
    auto dp4 = [&](float t0, float t1, float t2, float t3) -> float {
        const float z0 = t0 * fmaf(t0 * t0, C1, C0);
        const float z1 = t1 * fmaf(t1 * t1, C1, C0);
        const float z2 = t2 * fmaf(t2 * t2, C1, C0);
        const float z3 = t3 * fmaf(t3 * t3, C1, C0);
        const float u0 = 1.0f + EXP2F(z0);
        const float u1 = 1.0f + EXP2F(z1);
        const float u2 = 1.0f + EXP2F(z2);
        const float u3 = 1.0f + EXP2F(z3);
        const float r01 = __builtin_amdgcn_rcpf(u0 * u1);
        const float r23 = __builtin_amdgcn_rcpf(u2 * u3);
        float n0 = (wd4[0] * t0) * u1; n0 = fmaf(wd4[1] * t1, u0, n0);
        float n1 = (wd4[2] * t2) * u3; n1 = fmaf(wd4[3] * t3, u2, n1);
        float p  = n0 * r01;
        return fmaf(n1, r23, p);
    };

    float sum = 0.0f, sumsq = 0.0f;

    for (int s = 0; s < NPAIRT; ++s) {
        const int cw = 64 * s + lane;      // this lane's window element (= its y element)
        const int ws = cw + 1;             // short index of x[cw-3] in sxh

        const unsigned* pw = xhD + (ws >> 1);
        const unsigned sh = (unsigned)(ws & 1) * 16u;   // 0 or 16 (5-bit safe)
        const unsigned q0 = pw[0], q1 = pw[1], q2 = pw[2], q3 = pw[3], q4 = pw[4];
        union { unsigned u[4]; bf16x8 v; } bfr;
        bfr.u[0] = __builtin_amdgcn_alignbit(q1, q0, sh);
        bfr.u[1] = __builtin_amdgcn_alignbit(q2, q1, sh);
        bfr.u[2] = __builtin_amdgcn_alignbit(q3, q2, sh);
        bfr.u[3] = __builtin_amdgcn_alignbit(q4, q3, sh);

        f32x16 d = __builtin_amdgcn_mfma_f32_32x32x16_bf16(afrag, bfr.v, cin, 0, 0, 0);

        // d[0..3]: ranks rbase.. of eA=64s+l31 ; d[4..7]: same ranks of eB=eA+32
        const float pA = dp4(d[0], d[1], d[2], d[3]);
        const float pB = dp4(d[4], d[5], d[6], d[7]);
        const float hA = pA + __shfl_xor(pA, 32, 64);
        const float hB = pB + __shfl_xor(pB, 32, 64);
        const float h  = (hh == 0) ? hA : hB;          // this lane's element = cw

        const float xv = sxy[wv][cw];
        const float y  = xv + h;           // residual (bdown cancels in LN)
        sxy[wv][cw] = y;
        sum += y;
        sumsq = fmaf(y, y, sumsq);
    }

    // ---- tail tile: elements 832..861 (single-tile path, halves duplicate) ----
    {
        const int c  = 832 + l31;
        const int ws = c + 1;
        const unsigned* pw = xhD + (ws >> 1);
        const unsigned sh = (unsigned)(ws & 1) * 16u;
        const unsigned q0 = pw[0], q1 = pw[1], q2 = pw[2], q3 = pw[3], q4 = pw[4];
        union { unsigned u[4]; bf16x8 v; } bfr;
        bfr.u[0] = __builtin_amdgcn_alignbit(q1, q0, sh);
        bfr.u[1] = __builtin_amdgcn_alignbit(q2, q1, sh);
        bfr.u[2] = __builtin_amdgcn_alignbit(q3, q2, sh);
        bfr.u[3] = __builtin_amdgcn_alignbit(q4, q3, sh);

        f32x16 d = __builtin_amdgcn_mfma_f32_32x32x16_bf16(afrag, bfr.v, cin, 0, 0, 0);

        const float p = dp4(d[0], d[1], d[2], d[3]);
        const float psum = p + __shfl_xor(p, 32, 64);
        const float y = sxy[wv][c] + psum;
        if (hh == 0 && c < CDIM) {                     // single-counted
            sxy[wv][c] = y;
            sum += y;
            sumsq = fmaf(y, y, sumsq);
        }
    }

    // in-wave butterfly: every lane ends with the row totals
#pragma unroll
    for (int off = 1; off < 64; off <<= 1) {
        sum   += __shfl_xor(sum, off, 64);
        sumsq += __shfl_xor(sumsq, off, 64);
    }

    const float inv  = 1.0f / (float)CDIM;
    const float mu   = sum * inv;
    const float var  = fmaf(sumsq, inv, -mu * mu);
    const float rstd = rsqrtf(var + LN_EPS);

    // coalesced epilogue: contiguous float2 reads from LDS, float2 stores
    float2* __restrict__ yr2 = reinterpret_cast<float2*>(out + (size_t)row * CDIM);
    const float2* __restrict__ g2 = reinterpret_cast<const float2*>(gamma);
    const float2* __restrict__ b2 = reinterpret_cast<const float2*>(beta);
#pragma unroll
    for (int qq = 0; qq < 7; ++qq) {
        const int i = lane + 64 * qq;
        if (i < CDIM / 2) {
            const float2 yv = *reinterpret_cast<const float2*>(&sxy[wv][2 * i]);
            const float2 gv = g2[i];
            const float2 bv = b2[i];
            float2 o;
            o.x = fmaf((yv.x - mu) * rstd, gv.x, bv.x);
            o.y = fmaf((yv.y - mu) * rstd, gv.y, bv.y);
            yr2[i] = o;
        }
    }
}

extern "C" void kernel_launch(void* const* d_in, const int* in_sizes, int n_in,
                              void* d_out, int out_size, void* d_ws, size_t ws_size,
                              hipStream_t stream) {
    const float* x     = (const float*)d_in[0];
    const float* Wup   = (const float*)d_in[1];
    const float* bup   = (const float*)d_in[2];
    const float* Wdown = (const float*)d_in[3];
    const float* bdown = (const float*)d_in[4];   // cancels in LayerNorm; unused
    const float* gamma = (const float*)d_in[5];
    const float* beta  = (const float*)d_in[6];
    float* out = (float*)d_out;
    (void)bdown;

    const int nrows = out_size / CDIM;                 // 11520 (divisible by 4)
    const int nblk  = nrows / ROWS_PER_BLOCK;          // 2880
    cvmc_kernel<<<nblk, THREADS, 0, stream>>>(x, Wup, bup, Wdown, bdown,
                                              gamma, beta, out);
}

// Round 21
// 36.020 us; speedup vs baseline: 1.2489x; 1.0268x over previous
//
#include <hip/hip_runtime.h>
#include <math.h>

#define CDIM   862
#define NRANK  8
#define KW     7
#define ROWS_PER_BLOCK 4
#define THREADS (ROWS_PER_BLOCK * 64)
#define LN_EPS 1e-5f
#define NTILE  7             // 7 quad-tiles x 128 elements cover [-1,894] >= [0,861]
#define XH_LEN 912           // shorts: [0..3]=x[-4..-1]=0, [4+i]=bf16(x[i]), zeros to 911
#define XY_LEN 866           // f32: x (overwritten by pre-norm y) + pad

typedef __attribute__((ext_vector_type(8)))  short bf16x8;
typedef __attribute__((ext_vector_type(16))) float f32x16;

static __device__ __forceinline__ unsigned rne_bf16(float f) {
    const unsigned u = __float_as_uint(f);
    return (u + 0x7FFFu + ((u >> 16) & 1u)) >> 16;   // round-to-nearest-even
}

// v_exp_f32 IS 2^x on gfx950 (r20-validated). Fallback exact.
#if __has_builtin(__builtin_amdgcn_exp2f)
#define EXP2F(x) __builtin_amdgcn_exp2f(x)
#else
#define EXP2F(x) __expf((x) * 0.69314718055994530942f)
#endif

// One wave = one row. QUAD-TILE MFMA: A(32x16) holds Wup four ways --
//   rows  0- 7: taps at k=0..6   -> conv(E0)   (E0 = 128s+2*l31-1, odd)
//   rows  8-15: taps at k=8..14  -> conv(E2)   (E2 = E0+64)
//   rows 16-23: taps at k=1..7   -> conv(E0+1) (shift-by-one trick)
//   rows 24-31: taps at k=9..15  -> conv(E2+1)
// B column l31: k=0..7 = window(E0) [lane hh=0], k=8..15 = window(E2) [hh=1].
// E0 odd => window start short E0+1 is even => each lane reads 4 ALIGNED
// dwords at xhD[64s+lane .. +3]: no alignbit, no shift compute. One
// mfma_32x32x16_bf16 -> 128 elements x 8 ranks (14->7 MFMAs, 70->28 LDS
// reads per row). D reg->row=(reg&3)+8*(reg>>2)+4*hh (m74/m101-verified):
// d[0..3]=E0, d[4..7]=E2, d[8..11]=E1, d[12..15]=E3 (ranks 4hh..4hh+3).
// Two-shuffle combine (r16-safe pattern); hh=0 lanes finalize E0,E1 and
// hh=1 finalize E2,E3 -> single-counted; (unsigned)e<862 masks edges.
// dp4 GELU math identical to r20 (PASS, absmax 0.03125); bdown dropped.
__global__ __launch_bounds__(THREADS) void cvmc_kernel(
    const float* __restrict__ x,
    const float* __restrict__ Wup,
    const float* __restrict__ bup,
    const float* __restrict__ Wdown,
    const float* __restrict__ bdown,
    const float* __restrict__ gamma,
    const float* __restrict__ beta,
    float* __restrict__ out)
{
    const int lane = threadIdx.x & 63;
    const int wv   = threadIdx.x >> 6;
    const int row  = blockIdx.x * ROWS_PER_BLOCK + wv;

    __shared__ short sxh[ROWS_PER_BLOCK][XH_LEN];
    __shared__ float sxy[ROWS_PER_BLOCK][XY_LEN];

    const int hh    = lane >> 5;
    const int l31   = lane & 31;
    const int rbase = 4 * hh;          // this half-wave's rank group
    float bu4[4], wd4[4];
#pragma unroll
    for (int q = 0; q < 4; ++q) {
        bu4[q] = bup[rbase + q];
        wd4[q] = Wdown[rbase + q];
    }

    // ---- A fragment: 4 row-groups, tap shift by group (see header) ----
    bf16x8 afrag;
    {
        const int r    = l31 & 7;
        const int grp  = l31 >> 3;             // 0..3
        const bool use = ((grp & 1) == hh);    // grp0,2 live in hh=0 slots; 1,3 in hh=1
        const int  sft = grp >> 1;             // 0 or 1 (shift-by-one for E+1 rows)
#pragma unroll
        for (int j = 0; j < 8; ++j) {
            const int tap = j - sft;
            float wvv = (use && tap >= 0 && tap < KW) ? Wup[r * KW + tap] : 0.0f;
            afrag[j] = (short)(rne_bf16(wvv) & 0xFFFFu);
        }
    }

    // ---- C operand: bias; rank of D row (reg&3)+4hh for every reg group ----
    f32x16 cin;
#pragma unroll
    for (int i = 0; i < 16; ++i) cin[i] = bu4[i & 3];

    // ---- stage row: sxy = f32 x, sxh = bf16(RNE) base-4, pads zeroed ----
    {
        const float2* __restrict__ xr2 =
            reinterpret_cast<const float2*>(x + (size_t)row * CDIM);
        unsigned* xhW = reinterpret_cast<unsigned*>(&sxh[wv][0]);
#pragma unroll
        for (int qq = 0; qq < 7; ++qq) {
            const int i = lane + 64 * qq;               // float2 pair index
            if (i < CDIM / 2) {
                float2 v = xr2[i];
                *reinterpret_cast<float2*>(&sxy[wv][2 * i]) = v;
                xhW[2 + i] = rne_bf16(v.x) | (rne_bf16(v.y) << 16);
            }
        }
        if (lane < 2)        xhW[lane] = 0u;            // shorts 0..3 = x[-4..-1]
        else if (lane < 25)  xhW[431 + lane] = 0u;      // dwords 433..455 = shorts 866..911
        else if (lane < 29)  sxy[wv][862 + (lane - 25)] = 0.0f;
    }
    // wave-private LDS slice; same-wave DS ops complete in issue order -> no barrier

    // gelu(t) ~ t*sigmoid(1.5957691 t + 0.0713548 t^3); u = 1 + 2^z (log2e folded)
    const float C1 = -0.0713548162f * 1.44269504088896340736f;
    const float C0 = -1.5957691216f * 1.44269504088896340736f;

    const unsigned* xhD = reinterpret_cast<const unsigned*>(&sxh[wv][0]);

    auto dp4 = [&](float t0, float t1, float t2, float t3) -> float {
        const float z0 = t0 * fmaf(t0 * t0, C1, C0);
        const float z1 = t1 * fmaf(t1 * t1, C1, C0);
        const float z2 = t2 * fmaf(t2 * t2, C1, C0);
        const float z3 = t3 * fmaf(t3 * t3, C1, C0);
        const float u0 = 1.0f + EXP2F(z0);
        const float u1 = 1.0f + EXP2F(z1);
        const float u2 = 1.0f + EXP2F(z2);
        const float u3 = 1.0f + EXP2F(z3);
        const float r01 = __builtin_amdgcn_rcpf(u0 * u1);
        const float r23 = __builtin_amdgcn_rcpf(u2 * u3);
        float n0 = (wd4[0] * t0) * u1; n0 = fmaf(wd4[1] * t1, u0, n0);
        float n1 = (wd4[2] * t2) * u3; n1 = fmaf(wd4[3] * t3, u2, n1);
        float p  = n0 * r01;
        return fmaf(n1, r23, p);
    };

    float sum = 0.0f, sumsq = 0.0f;

    for (int s = 0; s < NTILE; ++s) {
        // this lane's window: 4 aligned dwords (8 bf16) -- its k-half of column l31
        const int w = 64 * s + lane;
        union { unsigned u[4]; bf16x8 v; } bfr;
        bfr.u[0] = xhD[w];
        bfr.u[1] = xhD[w + 1];
        bfr.u[2] = xhD[w + 2];
        bfr.u[3] = xhD[w + 3];

        f32x16 d = __builtin_amdgcn_mfma_f32_32x32x16_bf16(afrag, bfr.v, cin, 0, 0, 0);

        const float pE0 = dp4(d[0],  d[1],  d[2],  d[3]);    // ranks rbase.. of E0
        const float pE2 = dp4(d[4],  d[5],  d[6],  d[7]);    // of E2 = E0+64
        const float pE1 = dp4(d[8],  d[9],  d[10], d[11]);   // of E1 = E0+1
        const float pE3 = dp4(d[12], d[13], d[14], d[15]);   // of E3 = E2+1

        const float hE0 = pE0 + __shfl_xor(pE0, 32, 64);
        const float hE2 = pE2 + __shfl_xor(pE2, 32, 64);
        const float hE1 = pE1 + __shfl_xor(pE1, 32, 64);
        const float hE3 = pE3 + __shfl_xor(pE3, 32, 64);

        // ownership: hh=0 finalizes (E0,E1); hh=1 finalizes (E2,E3)
        const int   eS = 128 * s + 2 * l31 - 1 + 64 * hh;
        const float h0 = hh ? hE2 : hE0;
        const float h1 = hh ? hE3 : hE1;

        if ((unsigned)eS < CDIM) {
            const float y = sxy[wv][eS] + h0;
            sxy[wv][eS] = y;
            sum += y;
            sumsq = fmaf(y, y, sumsq);
        }
        if ((unsigned)(eS + 1) < CDIM) {
            const float y = sxy[wv][eS + 1] + h1;
            sxy[wv][eS + 1] = y;
            sum += y;
            sumsq = fmaf(y, y, sumsq);
        }
    }

    // in-wave butterfly: every lane ends with the row totals
#pragma unroll
    for (int off = 1; off < 64; off <<= 1) {
        sum   += __shfl_xor(sum, off, 64);
        sumsq += __shfl_xor(sumsq, off, 64);
    }

    const float inv  = 1.0f / (float)CDIM;
    const float mu   = sum * inv;
    const float var  = fmaf(sumsq, inv, -mu * mu);
    const float rstd = rsqrtf(var + LN_EPS);

    // coalesced epilogue: contiguous float2 reads from LDS, float2 stores
    float2* __restrict__ yr2 = reinterpret_cast<float2*>(out + (size_t)row * CDIM);
    const float2* __restrict__ g2 = reinterpret_cast<const float2*>(gamma);
    const float2* __restrict__ b2 = reinterpret_cast<const float2*>(beta);
#pragma unroll
    for (int qq = 0; qq < 7; ++qq) {
        const int i = lane + 64 * qq;
        if (i < CDIM / 2) {
            const float2 yv = *reinterpret_cast<const float2*>(&sxy[wv][2 * i]);
            const float2 gv = g2[i];
            const float2 bv = b2[i];
            float2 o;
            o.x = fmaf((yv.x - mu) * rstd, gv.x, bv.x);
            o.y = fmaf((yv.y - mu) * rstd, gv.y, bv.y);
            yr2[i] = o;
        }
    }
}

extern "C" void kernel_launch(void* const* d_in, const int* in_sizes, int n_in,
                              void* d_out, int out_size, void* d_ws, size_t ws_size,
                              hipStream_t stream) {
    const float* x     = (const float*)d_in[0];
    const float* Wup   = (const float*)d_in[1];
    const float* bup   = (const float*)d_in[2];
    const float* Wdown = (const float*)d_in[3];
    const float* bdown = (const float*)d_in[4];   // cancels in LayerNorm; unused
    const float* gamma = (const float*)d_in[5];
    const float* beta  = (const float*)d_in[6];
    float* out = (float*)d_out;
    (void)bdown;

    const int nrows = out_size / CDIM;                 // 11520 (divisible by 4)
    const int nblk  = nrows / ROWS_PER_BLOCK;          // 2880
    cvmc_kernel<<<nblk, THREADS, 0, stream>>>(x, Wup, bup, Wdown, bdown,
                                              gamma, beta, out);
}